// Round 10
// baseline (120.651 us; speedup 1.0000x reference)
//
#include <hip/hip_runtime.h>

// B=128, K=256, M=8, D=128 ; rows = B*K = 32768 flattened (b,k)
#define LT 20.0f        // lambda == gamma == 20
#define NBLK 512        // 512 blocks x 64 rows = all 32768 rows

typedef _Float16 half8 __attribute__((ext_vector_type(8)));
typedef float    f32x4 __attribute__((ext_vector_type(4)));

__device__ __forceinline__ float swz16(float x) {
    // xor lane^16 within 32-lane halves (BitMode: xor=16, and=0x1F)
    return __int_as_float(__builtin_amdgcn_ds_swizzle(__float_as_int(x), 0x401F));
}

// ---- prep: pack P f32->f16 into per-lane MFMA A-fragments.
// Fragment id = (u<<9)|(c<<7)|(s<<6)|lane, 8 halves each (16 B).
// For lane=(q,n): col = u*32 + (n>>2)*8 + (n&3) + s*4  (pair trick: s=0 -> protos
// 0-3 of concepts u*4..u*4+3, s=1 -> protos 4-7), k = c*32 + q*8 + j.
__global__ __launch_bounds__(256)
void mpcl_prep(const float* __restrict__ P, _Float16* __restrict__ Pw)
{
    int id   = blockIdx.x * 256 + threadIdx.x;   // 0..32767
    int lane = id & 63;
    int s    = (id >> 6) & 1;
    int c    = (id >> 7) & 3;
    int u    = id >> 9;                          // 0..63
    int n = lane & 15, q = lane >> 4;
    int col = u * 32 + ((n >> 2) << 3) + (n & 3) + s * 4;
    const float* src = P + (size_t)col * 128 + c * 32 + q * 8;
    float4 a = *(const float4*)src;
    float4 b = *(const float4*)(src + 4);
    half8 hv;
    hv[0] = (_Float16)a.x; hv[1] = (_Float16)a.y;
    hv[2] = (_Float16)a.z; hv[3] = (_Float16)a.w;
    hv[4] = (_Float16)b.x; hv[5] = (_Float16)b.y;
    hv[6] = (_Float16)b.z; hv[7] = (_Float16)b.w;
    *(half8*)&Pw[(size_t)id * 8] = hv;
}

// Grid: 512 blocks x 512 thr (8 waves) => 2 blocks/CU (LDS ~0.5 KB, VGPR<=128).
// Block = 64 rows x all 2048 cols. NO LDS staging, NO main-loop barriers:
// each wave loads its A-fragments directly from L2-resident packed Pw
// (16 B/lane contiguous => 1 KB coalesced per load). Race surface: none.
// wave w: rg=w>>2 -> 32 rows (rf 0..1 x 16); cq=w&3 -> units cq*16..cq*16+15
// (unit = 32 cols = 4 concepts). Pair trick: lane (q,n) ends with all 8 protos
// of concept u*4+q for V-row n in acc1+acc2 (round-5-verified).
__global__ __launch_bounds__(512, 2)
void mpcl_main(const float* __restrict__ V,        // (32768, 128)
               const int*   __restrict__ labels,   // (32768)
               const _Float16* __restrict__ Pw,    // packed A-fragments
               int* __restrict__ gcnt, float* __restrict__ gsum,
               float* __restrict__ out)
{
    __shared__ float sh_denom[64];
    __shared__ float sh_simpos[64];

    const int tid  = threadIdx.x;
    const int lane = tid & 63;
    const int w    = tid >> 6;        // 0..7
    const int rg   = w >> 2;          // 0..1 -> 32-row group
    const int cq   = w & 3;           // 0..3 -> 16-unit column quarter
    const int n    = lane & 15;
    const int q    = lane >> 4;
    const int rowbase = blockIdx.x * 64;

    if (tid < 64) { sh_denom[tid] = 0.0f; sh_simpos[tid] = 0.0f; }

    // ---- V fragments (B operand), f16, register-resident ----
    half8 vh[2][4];
#pragma unroll
    for (int rf = 0; rf < 2; ++rf) {
        const float* vr = V + (size_t)(rowbase + rg * 32 + rf * 16 + n) * 128 + q * 8;
#pragma unroll
        for (int c = 0; c < 4; ++c) {
            float4 x0 = *(const float4*)(vr + c * 32);
            float4 x1 = *(const float4*)(vr + c * 32 + 4);
            vh[rf][c][0] = (_Float16)x0.x; vh[rf][c][1] = (_Float16)x0.y;
            vh[rf][c][2] = (_Float16)x0.z; vh[rf][c][3] = (_Float16)x0.w;
            vh[rf][c][4] = (_Float16)x1.x; vh[rf][c][5] = (_Float16)x1.y;
            vh[rf][c][6] = (_Float16)x1.z; vh[rf][c][7] = (_Float16)x1.w;
        }
    }

    __syncthreads();   // sh_denom/sh_simpos init visible before loop writes

    const int rowk0 = (rowbase + rg * 32 + n) & 255;        // positive concept, rf=0
    const int rowk1 = (rowbase + rg * 32 + 16 + n) & 255;   // rf=1

    float dn[2] = {0.f, 0.f};

#pragma unroll 2
    for (int t = 0; t < 16; ++t) {
        const int u = cq * 16 + t;    // 32-col unit; concepts u*4 .. u*4+3
        const _Float16* bp = Pw + (((size_t)u << 9) + lane) * 8;

        f32x4 acc1[2] = {{0.f,0.f,0.f,0.f},{0.f,0.f,0.f,0.f}};
        f32x4 acc2[2] = {{0.f,0.f,0.f,0.f},{0.f,0.f,0.f,0.f}};
#pragma unroll
        for (int c = 0; c < 4; ++c) {
            half8 a1 = *(const half8*)(bp + c * 1024);         // s=0 frag
            half8 a2 = *(const half8*)(bp + c * 1024 + 512);   // s=1 frag
            acc1[0] = __builtin_amdgcn_mfma_f32_16x16x32_f16(a1, vh[0][c], acc1[0], 0, 0, 0);
            acc1[1] = __builtin_amdgcn_mfma_f32_16x16x32_f16(a1, vh[1][c], acc1[1], 0, 0, 0);
            acc2[0] = __builtin_amdgcn_mfma_f32_16x16x32_f16(a2, vh[0][c], acc2[0], 0, 0, 0);
            acc2[1] = __builtin_amdgcn_mfma_f32_16x16x32_f16(a2, vh[1][c], acc2[1], 0, 0, 0);
        }

        // ---- in-lane softmax over this concept's 8 protos (round-5 epilogue) ----
        const int cA = u * 4 + q;
#pragma unroll
        for (int rf = 0; rf < 2; ++rf) {
            float x0 = acc1[rf][0], x1 = acc1[rf][1], x2 = acc1[rf][2], x3 = acc1[rf][3];
            float x4 = acc2[rf][0], x5 = acc2[rf][1], x6 = acc2[rf][2], x7 = acc2[rf][3];
            float e0 = __expf(LT * x0), e1 = __expf(LT * x1);
            float e2 = __expf(LT * x2), e3 = __expf(LT * x3);
            float e4 = __expf(LT * x4), e5 = __expf(LT * x5);
            float e6 = __expf(LT * x6), e7 = __expf(LT * x7);
            float es = ((e0 + e1) + (e2 + e3)) + ((e4 + e5) + (e6 + e7));
            float ss = fmaf(e0, x0, fmaf(e1, x1, fmaf(e2, x2, e3 * x3)))
                     + fmaf(e4, x4, fmaf(e5, x5, fmaf(e6, x6, e7 * x7)));
            float simc = __fdividef(ss, es);
            dn[rf] += __expf(LT * simc);
            if (cA == (rf ? rowk1 : rowk0))
                sh_simpos[rg * 32 + rf * 16 + n] = simc;   // unique writer per row
        }
    }

    // ---- fold denominators over the 4 q-groups (distinct concepts) ----
#pragma unroll
    for (int rf = 0; rf < 2; ++rf) {
        float t = dn[rf];
        t += swz16(t);
        t += __shfl_xor(t, 32);
        if (lane < 16)
            atomicAdd(&sh_denom[rg * 32 + rf * 16 + n], t);
    }
    __syncthreads();

    // ---- in-block loss over 64 rows, one global atomic per block ----
    if (tid < 64) {
        int row = rowbase + tid;
        float lp = logf(sh_denom[tid] + 1e-8f) - LT * (sh_simpos[tid] + 0.05f);
        float mk = (labels[row] == 1) ? 1.0f : 0.0f;
        float s  = lp * mk;
        float cc = mk;
#pragma unroll
        for (int off = 32; off >= 1; off >>= 1) {
            s  += __shfl_down(s, off);
            cc += __shfl_down(cc, off);
        }
        if (lane == 0) {
            atomicAdd(&gsum[0], s);
            atomicAdd(&gsum[1], cc);
        }
    }

    // ---- all NBLK blocks arrive; last one finalizes ----
    if (tid == 0) {
        __threadfence();
        int g = __hip_atomic_fetch_add(gcnt, 1,
                                       __ATOMIC_ACQ_REL, __HIP_MEMORY_SCOPE_AGENT);
        if (g == NBLK - 1) {
            __threadfence();
            float ts = __hip_atomic_load(&gsum[0], __ATOMIC_RELAXED, __HIP_MEMORY_SCOPE_AGENT);
            float tc = __hip_atomic_load(&gsum[1], __ATOMIC_RELAXED, __HIP_MEMORY_SCOPE_AGENT);
            out[0] = (tc > 0.0f) ? (ts / tc) : ts;
        }
    }
}

extern "C" void kernel_launch(void* const* d_in, const int* in_sizes, int n_in,
                              void* d_out, int out_size, void* d_ws, size_t ws_size,
                              hipStream_t stream)
{
    const float* V      = (const float*)d_in[0];
    const int*   labels = (const int*)d_in[1];
    const float* P      = (const float*)d_in[2];
    float* out = (float*)d_out;

    // ws: [0,64) counters (gcnt@0, gsum@8); Pw at [64, 524352) — proven footprint.
    int*   wsi  = (int*)d_ws;
    int*   gcnt = wsi;
    float* gsum = (float*)(wsi + 2);
    _Float16* Pw = (_Float16*)((char*)d_ws + 64);

    hipMemsetAsync(d_ws, 0, 64, stream);
    mpcl_prep<<<128, 256, 0, stream>>>(P, Pw);
    mpcl_main<<<NBLK, 512, 0, stream>>>(V, labels, Pw, gcnt, gsum, out);
}